// Round 17
// baseline (91.720 us; speedup 1.0000x reference)
//
#include <hip/hip_runtime.h>
#include <hip/hip_bf16.h>
#include <math.h>

#define B_ 8
#define S_ 4096
#define C_ 64
#define EPSV 1e-5f

using floatx4 = __attribute__((ext_vector_type(4))) float;
using bf16x8  = __attribute__((ext_vector_type(8))) short;
using bf16x4  = __attribute__((ext_vector_type(4))) short;
using intx4   = __attribute__((ext_vector_type(4))) int;

typedef __attribute__((address_space(3))) unsigned int       as3_u32;
typedef __attribute__((address_space(1))) const unsigned int as1_u32;

__device__ __forceinline__ short f2bf(float f) {
    unsigned u = __builtin_bit_cast(unsigned, f);
    u = u + 0x7fffu + ((u >> 16) & 1u);   // RNE
    return (short)(u >> 16);
}

__device__ __forceinline__ float bf2f(short s) {
    return __builtin_bit_cast(float, ((unsigned)(unsigned short)s) << 16);
}

__device__ __forceinline__ unsigned cvt_pk_bf16(float lo, float hi) {
    unsigned r;
    asm volatile("v_cvt_pk_bf16_f32 %0, %1, %2" : "=v"(r) : "v"(lo), "v"(hi));
    return r;
}

// B-fragment from a row-major fp32 64x64 weight matrix.
__device__ __forceinline__ bf16x8 ld_w_frag(const float* __restrict__ W, int n, int kk, int g, int c) {
    const float* p = W + (16 * n + c) * C_ + 32 * kk + 8 * g;
    bf16x8 r;
#pragma unroll
    for (int j = 0; j < 8; ++j) r[j] = f2bf(p[j]);
    return r;
}

// ---------------- kernel 1a: per-chunk partial sums ----------------
__global__ __launch_bounds__(256) void stats1_kernel(const float* __restrict__ x,
                                                     float* __restrict__ partial) {
    int b = blockIdx.x >> 5, chunk = blockIdx.x & 31;
    const float4* xb = (const float4*)x + (size_t)b * 65536 + chunk * 2048;
    float s = 0.f, ss = 0.f;
#pragma unroll
    for (int i = 0; i < 8; ++i) {
        float4 v = xb[threadIdx.x + i * 256];
        s  += v.x + v.y + v.z + v.w;
        ss += v.x * v.x + v.y * v.y + v.z * v.z + v.w * v.w;
    }
    for (int off = 32; off > 0; off >>= 1) {
        s  += __shfl_down(s, off);
        ss += __shfl_down(ss, off);
    }
    __shared__ float sm[4], ssm[4];
    int wid = threadIdx.x >> 6, lane = threadIdx.x & 63;
    if (lane == 0) { sm[wid] = s; ssm[wid] = ss; }
    __syncthreads();
    if (threadIdx.x == 0) {
        partial[blockIdx.x * 2]     = sm[0] + sm[1] + sm[2] + sm[3];
        partial[blockIdx.x * 2 + 1] = ssm[0] + ssm[1] + ssm[2] + ssm[3];
    }
}

// ---------------- kernel 1b: finalize mean / rsqrt(var) ----------------
__global__ __launch_bounds__(512) void stats2_kernel(const float* __restrict__ partial,
                                                     float* __restrict__ stats) {
    int w = threadIdx.x >> 6, lane = threadIdx.x & 63;  // wave w = batch w
    float s = 0.f, ss = 0.f;
    if (lane < 32) {
        s  = partial[(w * 32 + lane) * 2];
        ss = partial[(w * 32 + lane) * 2 + 1];
    }
    for (int off = 16; off > 0; off >>= 1) {
        s  += __shfl_down(s, off);
        ss += __shfl_down(ss, off);
    }
    if (lane == 0) {
        const float invN = 1.0f / (float)(S_ * C_);
        float mu  = s * invN;
        float var = ss * invN - mu * mu;
        stats[w * 2]     = mu;
        stats[w * 2 + 1] = rsqrtf(var + EPSV);
    }
}

// ---------------- kernel 2: normalize + Q/K/V^T projections ----------------
// K and V^T tile images (32-kv, 4096 B) built in LDS then dumped coalesced.
//   K tile:  [32 kv][64 ch] bf16, byte = (r32*128 + ch*2) ^ ((r32&7)<<4)
//   V tile:  [64 ch][32 kv] bf16, byte = (ch*64 + u32*2) ^ (((ch>>1)&3)<<4)
// (V swizzle moved to 16B granule so flash's b128 V reads stay contiguous.)
__global__ __launch_bounds__(256) void proj_kernel(
    const float* __restrict__ x,
    const float* __restrict__ Wq, const float* __restrict__ bq,
    const float* __restrict__ Wk, const float* __restrict__ bk,
    const float* __restrict__ Wv, const float* __restrict__ bv,
    const float* __restrict__ stats,
    short* __restrict__ qo, char* __restrict__ kws, char* __restrict__ vws) {
    __shared__ char hbuf[8192];   // [64 rows][64 bf16], XOR-swizzled
    __shared__ char kimg[8192];   // 2 x 4KB K tile images
    __shared__ char vimg[8192];   // 2 x 4KB V tile images

    int b  = blockIdx.x >> 6;
    int t_ = blockIdx.x & 63;        // 64-row tile index within batch
    int s0 = t_ * 64;
    float mu = stats[b * 2], rs = stats[b * 2 + 1];
    const float* xt = x + ((size_t)b * S_ + s0) * C_;
    int t = threadIdx.x;

#pragma unroll
    for (int i = 0; i < 4; ++i) {
        int fi  = t + 256 * i;       // float4 index within 64x64 tile
        int row = fi >> 4;
        int c4  = fi & 15;
        float4 v = *(const float4*)(xt + row * C_ + c4 * 4);
        unsigned lo = (unsigned)(unsigned short)f2bf((v.x - mu) * rs) |
                      ((unsigned)(unsigned short)f2bf((v.y - mu) * rs) << 16);
        unsigned hi = (unsigned)(unsigned short)f2bf((v.z - mu) * rs) |
                      ((unsigned)(unsigned short)f2bf((v.w - mu) * rs) << 16);
        int off = row * 128 + c4 * 8;
        off ^= (row & 7) << 4;
        *(uint2*)(hbuf + off) = make_uint2(lo, hi);
    }
    __syncthreads();

    int lane = t & 63, w = t >> 6;
    int g = lane >> 4, c = lane & 15;

    auto ld_h = [&](int row, int kcol) -> bf16x8 {
        int off = row * 128 + kcol * 2;
        off ^= (row & 7) << 4;
        return *(const bf16x8*)(hbuf + off);
    };

    // ---- Q and K: D = h @ W^T.  A = h rows 16w..16w+15 ----
    bf16x8 ha[2];
    ha[0] = ld_h(16 * w + c, 8 * g);
    ha[1] = ld_h(16 * w + c, 32 + 8 * g);

    const float QSC = 0.125f * 1.44269504088896340736f;  // C^-0.5 * log2(e)

#pragma unroll
    for (int n = 0; n < 4; ++n) {
        floatx4 aq = {0.f, 0.f, 0.f, 0.f}, ak = {0.f, 0.f, 0.f, 0.f};
#pragma unroll
        for (int kk = 0; kk < 2; ++kk) {
            bf16x8 wq = ld_w_frag(Wq, n, kk, g, c);
            bf16x8 wk = ld_w_frag(Wk, n, kk, g, c);
            aq = __builtin_amdgcn_mfma_f32_16x16x32_bf16(ha[kk], wq, aq, 0, 0, 0);
            ak = __builtin_amdgcn_mfma_f32_16x16x32_bf16(ha[kk], wk, ak, 0, 0, 0);
        }
        float bqv = bq[16 * n + c], bkv = bk[16 * n + c];
#pragma unroll
        for (int r = 0; r < 4; ++r) {
            int rr = 16 * w + 4 * g + r;          // kv row within 64-row tile
            qo[((size_t)b * S_ + s0 + rr) * C_ + 16 * n + c] = f2bf((aq[r] + bqv) * QSC);
            int r32 = rr & 31;
            int koff = (r32 * 128 + (16 * n + c) * 2) ^ ((r32 & 7) << 4);
            *(short*)(kimg + (rr >> 5) * 4096 + koff) = f2bf(ak[r] + bkv);
        }
    }

    // ---- V^T = Wv @ h^T (direct transposed, 32-kv swizzled tile images) ----
    bf16x8 wv[2];
    wv[0] = ld_w_frag(Wv, w, 0, g, c);
    wv[1] = ld_w_frag(Wv, w, 1, g, c);
    float bvr[4];
#pragma unroll
    for (int r = 0; r < 4; ++r) bvr[r] = bv[16 * w + 4 * g + r];

#pragma unroll
    for (int n = 0; n < 4; ++n) {
        floatx4 av = {0.f, 0.f, 0.f, 0.f};
#pragma unroll
        for (int kk = 0; kk < 2; ++kk) {
            bf16x8 hb = ld_h(16 * n + c, 32 * kk + 8 * g);
            av = __builtin_amdgcn_mfma_f32_16x16x32_bf16(wv[kk], hb, av, 0, 0, 0);
        }
        int u   = 16 * n + c;                  // kv col within 64-row tile
        int u32 = u & 31;
#pragma unroll
        for (int r = 0; r < 4; ++r) {
            int rr = 16 * w + 4 * g + r;          // channel row
            int voff = (rr * 64 + u32 * 2) ^ (((rr >> 1) & 3) << 4);
            *(short*)(vimg + (u >> 5) * 4096 + voff) = f2bf(av[r] + bvr[r]);
        }
    }
    __syncthreads();

    // ---- coalesced dump: 16B/lane, both 4KB tiles of K and V ----
    size_t gb = ((size_t)b * 128 + 2 * t_) * 4096;
#pragma unroll
    for (int i = 0; i < 2; ++i) {
        *(uint4*)(kws + gb + i * 4096 + t * 16) = *(const uint4*)(kimg + i * 4096 + t * 16);
        *(uint4*)(vws + gb + i * 4096 + t * 16) = *(const uint4*)(vimg + i * 4096 + t * 16);
    }
}

// ---------------- kernel 3: full-rate-PV pipelined flash attention ----------------
// R16 structure (32q/wave, 4-way KV split, 3-buf counted vmcnt) but PV now uses
// the NATIVE K=32 MFMA: cross-round MfmaUtil fits show legacy 16x16x16 bf16 runs
// ~20cyc (quarter rate) -> PV was 320cyc/tile of matrix pipe. B-fragment for
// K=32 built via R0-proven 8x ds_bpermute + 4 cndmask per q-subtile.
__global__ __launch_bounds__(256, 4) void flash_kernel(
    const short* __restrict__ qm, const char* __restrict__ kws, const char* __restrict__ vws,
    short* __restrict__ Opart, float2* __restrict__ mlpart) {
    __shared__ char lds[24576];   // [0,12K): 3 K bufs; [12K,24K): 3 V bufs

    int bid = blockIdx.x;
    int logical = (bid & 7) * 128 + (bid >> 3);  // XCD swizzle: batch b -> XCD b
    int b = logical >> 7;
    int rest = logical & 127;
    int q0 = (rest >> 2) * 128;
    int quarter = rest & 3;
    int t = threadIdx.x;
    int lane = t & 63, w = t >> 6;
    int g = lane >> 4, c = lane & 15;
    int qw = q0 + 32 * w;

    const char* kbase = kws + (size_t)b * 128 * 4096;
    const char* vbase = vws + (size_t)b * 128 * 4096;
    const short* qp = qm + (size_t)b * S_ * C_;

    // Q^T B-fragments for this wave's two 16-row q-subtiles.
    bf16x8 bqf[2][2];
#pragma unroll
    for (int qi = 0; qi < 2; ++qi) {
        bqf[qi][0] = *(const bf16x8*)(qp + (qw + 16 * qi + c) * C_ + 8 * g);
        bqf[qi][1] = *(const bf16x8*)(qp + (qw + 16 * qi + c) * C_ + 32 + 8 * g);
    }

    floatx4 oacc[2][4];               // [qi][mi]
#pragma unroll
    for (int qi = 0; qi < 2; ++qi)
#pragma unroll
        for (int mi = 0; mi < 4; ++mi) oacc[qi][mi] = (floatx4){0.f, 0.f, 0.f, 0.f};
    float m[2] = {-__builtin_inff(), -__builtin_inff()}, l[2] = {0.f, 0.f};

    const int xmask  = (c & 7) << 4;          // K row swizzle (16B granule)
    const int vxmask = ((c >> 1) & 3) << 4;   // V row swizzle (16B granule)
    const int addr0 = (32 * (g & 1) + c) * 4; // bpermute src lane*4
    const int addr1 = addr0 + 64;
    const bool kbhi = (g >> 1) != 0;

    auto STAGE = [&](int bi, int tt) {
        const char* gk = kbase + (size_t)tt * 4096 + t * 16;
        const char* gv = vbase + (size_t)tt * 4096 + t * 16;
        char* lk = lds +         bi * 4096 + t * 16;
        char* lv = lds + 12288 + bi * 4096 + t * 16;
        __builtin_amdgcn_global_load_lds((as1_u32*)gk, (as3_u32*)lk, 16, 0, 0);
        __builtin_amdgcn_global_load_lds((as1_u32*)gv, (as3_u32*)lv, 16, 0, 0);
    };

    // K read: kv row = 16*s + c, col bytes colb (16B granule)
    auto ld_k = [&](const char* buf, int s, int colb) -> bf16x8 {
        return *(const bf16x8*)(buf + s * 2048 + c * 128 + (colb ^ xmask));
    };
    // V read (16B): ch row = 16*mi + c, kv = 8g..8g+7 (A-frag for K=32 MFMA)
    auto ld_v = [&](const char* buf, int mi) -> bf16x8 {
        return *(const bf16x8*)(buf + mi * 1024 + c * 64 + ((16 * g) ^ vxmask));
    };

    auto COMPUTE = [&](int bi) {
        const char* kbuf = lds +         bi * 4096;
        const char* vbuf = lds + 12288 + bi * 4096;
        // K fragments read ONCE, reused for both q-subtiles
        bf16x8 ak[2][2];
#pragma unroll
        for (int s = 0; s < 2; ++s)
#pragma unroll
            for (int kk = 0; kk < 2; ++kk)
                ak[s][kk] = ld_k(kbuf, s, 64 * kk + 16 * g);
        // ---- S^T (32 kv x 32 q) ----
        floatx4 st[2][2];
        __builtin_amdgcn_s_setprio(1);
#pragma unroll
        for (int qi = 0; qi < 2; ++qi)
#pragma unroll
            for (int s = 0; s < 2; ++s) {
                st[qi][s] = (floatx4){0.f, 0.f, 0.f, 0.f};
                st[qi][s] = __builtin_amdgcn_mfma_f32_16x16x32_bf16(ak[s][0], bqf[qi][0], st[qi][s], 0, 0, 0);
                st[qi][s] = __builtin_amdgcn_mfma_f32_16x16x32_bf16(ak[s][1], bqf[qi][1], st[qi][s], 0, 0, 0);
            }
        __builtin_amdgcn_s_setprio(0);
        // V fragments read ONCE (independent of softmax; issued early)
        bf16x8 av[4];
#pragma unroll
        for (int mi = 0; mi < 4; ++mi)
            av[mi] = ld_v(vbuf, mi);
        // ---- online softmax per q-subtile; joint rescale branch ----
        float mt[2], need = -1e30f;
#pragma unroll
        for (int qi = 0; qi < 2; ++qi) {
            float v = fmaxf(fmaxf(st[qi][0][0], st[qi][0][1]), fmaxf(st[qi][0][2], st[qi][0][3]));
            v = fmaxf(v, fmaxf(fmaxf(st[qi][1][0], st[qi][1][1]), fmaxf(st[qi][1][2], st[qi][1][3])));
            v = fmaxf(v, __shfl_xor(v, 16));
            v = fmaxf(v, __shfl_xor(v, 32));
            mt[qi] = v;
            need = fmaxf(need, v - m[qi]);
        }
        if (!__all(need <= 8.0f)) {
#pragma unroll
            for (int qi = 0; qi < 2; ++qi) {
                float mn = fmaxf(m[qi], mt[qi]);
                float a  = __builtin_amdgcn_exp2f(m[qi] - mn);
                m[qi] = mn;
                l[qi] *= a;
#pragma unroll
                for (int mi = 0; mi < 4; ++mi) oacc[qi][mi] *= a;
            }
        }
        // ---- P + redistribution into K=32 B-fragment (R0 mapping) + PV ----
        __builtin_amdgcn_s_setprio(1);
#pragma unroll
        for (int qi = 0; qi < 2; ++qi) {
            float e0 = __builtin_amdgcn_exp2f(st[qi][0][0] - m[qi]);
            float e1 = __builtin_amdgcn_exp2f(st[qi][0][1] - m[qi]);
            float e2 = __builtin_amdgcn_exp2f(st[qi][0][2] - m[qi]);
            float e3 = __builtin_amdgcn_exp2f(st[qi][0][3] - m[qi]);
            float e4 = __builtin_amdgcn_exp2f(st[qi][1][0] - m[qi]);
            float e5 = __builtin_amdgcn_exp2f(st[qi][1][1] - m[qi]);
            float e6 = __builtin_amdgcn_exp2f(st[qi][1][2] - m[qi]);
            float e7 = __builtin_amdgcn_exp2f(st[qi][1][3] - m[qi]);
            l[qi] += ((e0 + e1) + (e2 + e3)) + ((e4 + e5) + (e6 + e7));
            unsigned pk00 = cvt_pk_bf16(e0, e1);
            unsigned pk01 = cvt_pk_bf16(e2, e3);
            unsigned pk10 = cvt_pk_bf16(e4, e5);
            unsigned pk11 = cvt_pk_bf16(e6, e7);
            int w0a = __builtin_amdgcn_ds_bpermute(addr0, (int)pk00);
            int w0b = __builtin_amdgcn_ds_bpermute(addr0, (int)pk10);
            int w1a = __builtin_amdgcn_ds_bpermute(addr0, (int)pk01);
            int w1b = __builtin_amdgcn_ds_bpermute(addr0, (int)pk11);
            int w2a = __builtin_amdgcn_ds_bpermute(addr1, (int)pk00);
            int w2b = __builtin_amdgcn_ds_bpermute(addr1, (int)pk10);
            int w3a = __builtin_amdgcn_ds_bpermute(addr1, (int)pk01);
            int w3b = __builtin_amdgcn_ds_bpermute(addr1, (int)pk11);
            intx4 bpw;
            bpw[0] = kbhi ? w0b : w0a;
            bpw[1] = kbhi ? w1b : w1a;
            bpw[2] = kbhi ? w2b : w2a;
            bpw[3] = kbhi ? w3b : w3a;
            bf16x8 bp = __builtin_bit_cast(bf16x8, bpw);
#pragma unroll
            for (int mi = 0; mi < 4; ++mi)
                oacc[qi][mi] = __builtin_amdgcn_mfma_f32_16x16x32_bf16(av[mi], bp, oacc[qi][mi], 0, 0, 0);
        }
        __builtin_amdgcn_s_setprio(0);
    };

    const int base = quarter * 32;
    STAGE(0, base);
    STAGE(1, base + 1);
    asm volatile("s_waitcnt vmcnt(2)" ::: "memory");   // tile 0 landed; tile 1 in flight
    __builtin_amdgcn_s_barrier();
    __builtin_amdgcn_sched_barrier(0);

    for (int r = 0; r < 32; ++r) {
        if (r < 30) STAGE((r + 2) % 3, base + r + 2);
        COMPUTE(r % 3);
        if (r < 31) {
            if (r < 30) asm volatile("s_waitcnt vmcnt(2)" ::: "memory");
            else        asm volatile("s_waitcnt vmcnt(0)" ::: "memory");
            __builtin_amdgcn_s_barrier();
            __builtin_amdgcn_sched_barrier(0);
        }
    }

    // ---- finalize: l reduce across lane groups; write (M,L) + bf16 partial ----
#pragma unroll
    for (int qi = 0; qi < 2; ++qi) {
        l[qi] += __shfl_xor(l[qi], 16);
        l[qi] += __shfl_xor(l[qi], 32);
    }

    size_t prow = (size_t)(quarter * 8 + b) * S_ + q0;
    if (lane < 16) {
#pragma unroll
        for (int qi = 0; qi < 2; ++qi)
            mlpart[prow + 32 * w + 16 * qi + lane] = make_float2(m[qi], l[qi]);
    }

#pragma unroll
    for (int qi = 0; qi < 2; ++qi) {
        short* op = Opart + (prow + 32 * w + 16 * qi + c) * C_;
#pragma unroll
        for (int mi = 0; mi < 4; ++mi) {
            uint2 u = make_uint2(cvt_pk_bf16(oacc[qi][mi][0], oacc[qi][mi][1]),
                                 cvt_pk_bf16(oacc[qi][mi][2], oacc[qi][mi][3]));
            *(uint2*)(op + 16 * mi + 4 * g) = u;
        }
    }
}

// ---------------- kernel 4: 4-way LSE combine + Wo + residual ----------------
__global__ __launch_bounds__(256) void combine_kernel(
    const short* __restrict__ Opart, const float2* __restrict__ mlpart,
    const float* __restrict__ Wo, const float* __restrict__ bo,
    const float* __restrict__ x, float* __restrict__ out) {
    __shared__ char obuf[8192];   // [64 q][64 ch] bf16, XOR-swizzled

    int bid = blockIdx.x;
    int logical = (bid & 7) * 64 + (bid >> 3);  // XCD swizzle: batch b -> XCD b
    int b = logical >> 6;
    int q0 = (logical & 63) * 64;
    int t = threadIdx.x;
    int lane = t & 63, w = t >> 6;
    int g = lane >> 4, c = lane & 15;

    const short*  P[4];
    const float2* ml[4];
#pragma unroll
    for (int h = 0; h < 4; ++h) {
        P[h]  = Opart  + ((size_t)(h * 8 + b) * S_ + q0) * C_;
        ml[h] = mlpart + (size_t)(h * 8 + b) * S_ + q0;
    }

#pragma unroll
    for (int i = 0; i < 16; ++i) {
        int idx = t + 256 * i;
        int q = idx >> 6, ch = idx & 63;
        float2 a0 = ml[0][q], a1 = ml[1][q], a2 = ml[2][q], a3 = ml[3][q];
        float M = fmaxf(fmaxf(a0.x, a1.x), fmaxf(a2.x, a3.x));
        float s0 = __builtin_amdgcn_exp2f(a0.x - M);
        float s1 = __builtin_amdgcn_exp2f(a1.x - M);
        float s2 = __builtin_amdgcn_exp2f(a2.x - M);
        float s3 = __builtin_amdgcn_exp2f(a3.x - M);
        float L  = a0.y * s0 + a1.y * s1 + a2.y * s2 + a3.y * s3;
        float o  = (bf2f(P[0][q * 64 + ch]) * s0 + bf2f(P[1][q * 64 + ch]) * s1 +
                    bf2f(P[2][q * 64 + ch]) * s2 + bf2f(P[3][q * 64 + ch]) * s3) / L;
        int off = (q * 128 + ch * 2) ^ ((q & 7) << 4);
        *(short*)(obuf + off) = f2bf(o);
    }
    __syncthreads();

    // wave w handles q rows q0+16w..+15; out = o @ Wo^T + bo + x
    bf16x8 ao[2];
    {
        int row = 16 * w + c;
        int off0 = (row * 128 + (8 * g) * 2)      ^ ((row & 7) << 4);
        int off1 = (row * 128 + (32 + 8 * g) * 2) ^ ((row & 7) << 4);
        ao[0] = *(const bf16x8*)(obuf + off0);
        ao[1] = *(const bf16x8*)(obuf + off1);
    }
#pragma unroll
    for (int n = 0; n < 4; ++n) {
        floatx4 a = {0.f, 0.f, 0.f, 0.f};
#pragma unroll
        for (int kk = 0; kk < 2; ++kk) {
            bf16x8 bw = ld_w_frag(Wo, n, kk, g, c);
            a = __builtin_amdgcn_mfma_f32_16x16x32_bf16(ao[kk], bw, a, 0, 0, 0);
        }
        float bov = bo[16 * n + c];
#pragma unroll
        for (int r = 0; r < 4; ++r) {
            int srow = q0 + 16 * w + 4 * g + r;
            size_t idx = ((size_t)b * S_ + srow) * C_ + 16 * n + c;
            out[idx] = x[idx] + bov + a[r];
        }
    }
}

extern "C" void kernel_launch(void* const* d_in, const int* in_sizes, int n_in,
                              void* d_out, int out_size, void* d_ws, size_t ws_size,
                              hipStream_t stream) {
    const float* x  = (const float*)d_in[0];
    // d_in[1] = temb (unused by reference)
    const float* Wq = (const float*)d_in[2];
    const float* bq = (const float*)d_in[3];
    const float* Wk = (const float*)d_in[4];
    const float* bk = (const float*)d_in[5];
    const float* Wv = (const float*)d_in[6];
    const float* bv = (const float*)d_in[7];
    const float* Wo = (const float*)d_in[8];
    const float* bo = (const float*)d_in[9];
    float* out = (float*)d_out;

    char* ws = (char*)d_ws;
    float*  partial = (float*)ws;                       // 512 floats
    float*  stats   = (float*)(ws + 2048);              // 16 floats
    short*  q   = (short*)(ws + 4096);                  // [B][S][C] bf16 (4 MB)
    char*   kt  = (char*)(q + (size_t)B_ * S_ * C_);    // [B][128][4096] swizzled K (4 MB)
    char*   vt  = kt + (size_t)B_ * 128 * 4096;         // [B][128][4096] swizzled V^T (4 MB)
    short*  op  = (short*)(vt + (size_t)B_ * 128 * 4096);// [4][B][S][C] bf16 partials (16 MB)
    float2* mlp = (float2*)((char*)op + (size_t)4 * B_ * S_ * C_ * 2); // [4][B][S] (1 MB)

    stats1_kernel<<<256, 256, 0, stream>>>(x, partial);
    stats2_kernel<<<1, 512, 0, stream>>>(partial, stats);
    proj_kernel<<<B_ * (S_ / 64), 256, 0, stream>>>(x, Wq, bq, Wk, bk, Wv, bv, stats, q, kt, vt);
    flash_kernel<<<B_ * (S_ / 128) * 4, 256, 0, stream>>>(q, kt, vt, op, mlp);
    combine_kernel<<<B_ * (S_ / 64), 256, 0, stream>>>(op, mlp, Wo, bo, x, out);
}

// Round 18
// 85.819 us; speedup vs baseline: 1.0688x; 1.0688x over previous
//
#include <hip/hip_runtime.h>
#include <hip/hip_bf16.h>
#include <math.h>

#define B_ 8
#define S_ 4096
#define C_ 64
#define EPSV 1e-5f

using floatx4 = __attribute__((ext_vector_type(4))) float;
using bf16x8  = __attribute__((ext_vector_type(8))) short;
using bf16x4  = __attribute__((ext_vector_type(4))) short;

typedef __attribute__((address_space(3))) unsigned int       as3_u32;
typedef __attribute__((address_space(1))) const unsigned int as1_u32;

__device__ __forceinline__ short f2bf(float f) {
    unsigned u = __builtin_bit_cast(unsigned, f);
    u = u + 0x7fffu + ((u >> 16) & 1u);   // RNE
    return (short)(u >> 16);
}

__device__ __forceinline__ float bf2f(short s) {
    return __builtin_bit_cast(float, ((unsigned)(unsigned short)s) << 16);
}

__device__ __forceinline__ unsigned cvt_pk_bf16(float lo, float hi) {
    unsigned r;
    asm volatile("v_cvt_pk_bf16_f32 %0, %1, %2" : "=v"(r) : "v"(lo), "v"(hi));
    return r;
}

// PV MFMA: 16x16x16 bf16 (K=16) — B-fragment layout (col=c, k=4g+j) matches
// the swapped-QK^T accumulator layout directly -> no cross-lane redistribution.
__device__ __forceinline__ floatx4 mfma_16x16x16_bf16(bf16x4 a, bf16x4 b, floatx4 c) {
#if __has_builtin(__builtin_amdgcn_mfma_f32_16x16x16bf16_1k)
    return __builtin_amdgcn_mfma_f32_16x16x16bf16_1k(a, b, c, 0, 0, 0);
#else
    asm("v_mfma_f32_16x16x16_bf16 %0, %1, %2, %0" : "+v"(c) : "v"(a), "v"(b));
    return c;
#endif
}

// B-fragment from a row-major fp32 64x64 weight matrix.
__device__ __forceinline__ bf16x8 ld_w_frag(const float* __restrict__ W, int n, int kk, int g, int c) {
    const float* p = W + (16 * n + c) * C_ + 32 * kk + 8 * g;
    bf16x8 r;
#pragma unroll
    for (int j = 0; j < 8; ++j) r[j] = f2bf(p[j]);
    return r;
}

// ---------------- kernel 1a: per-chunk partial sums ----------------
__global__ __launch_bounds__(256) void stats1_kernel(const float* __restrict__ x,
                                                     float* __restrict__ partial) {
    int b = blockIdx.x >> 5, chunk = blockIdx.x & 31;
    const float4* xb = (const float4*)x + (size_t)b * 65536 + chunk * 2048;
    float s = 0.f, ss = 0.f;
#pragma unroll
    for (int i = 0; i < 8; ++i) {
        float4 v = xb[threadIdx.x + i * 256];
        s  += v.x + v.y + v.z + v.w;
        ss += v.x * v.x + v.y * v.y + v.z * v.z + v.w * v.w;
    }
    for (int off = 32; off > 0; off >>= 1) {
        s  += __shfl_down(s, off);
        ss += __shfl_down(ss, off);
    }
    __shared__ float sm[4], ssm[4];
    int wid = threadIdx.x >> 6, lane = threadIdx.x & 63;
    if (lane == 0) { sm[wid] = s; ssm[wid] = ss; }
    __syncthreads();
    if (threadIdx.x == 0) {
        partial[blockIdx.x * 2]     = sm[0] + sm[1] + sm[2] + sm[3];
        partial[blockIdx.x * 2 + 1] = ssm[0] + ssm[1] + ssm[2] + ssm[3];
    }
}

// ---------------- kernel 1b: finalize mean / rsqrt(var) ----------------
__global__ __launch_bounds__(512) void stats2_kernel(const float* __restrict__ partial,
                                                     float* __restrict__ stats) {
    int w = threadIdx.x >> 6, lane = threadIdx.x & 63;  // wave w = batch w
    float s = 0.f, ss = 0.f;
    if (lane < 32) {
        s  = partial[(w * 32 + lane) * 2];
        ss = partial[(w * 32 + lane) * 2 + 1];
    }
    for (int off = 16; off > 0; off >>= 1) {
        s  += __shfl_down(s, off);
        ss += __shfl_down(ss, off);
    }
    if (lane == 0) {
        const float invN = 1.0f / (float)(S_ * C_);
        float mu  = s * invN;
        float var = ss * invN - mu * mu;
        stats[w * 2]     = mu;
        stats[w * 2 + 1] = rsqrtf(var + EPSV);
    }
}

// ---------------- kernel 2: normalize + Q/K/V^T projections ----------------
// K and V^T are written as per-32-kv TILE IMAGES (4096 B each), XOR-swizzled
// exactly as the flash kernel's LDS wants them (both-sides rule).
//   K tile:  [32 kv][64 ch] bf16, byte = (r32*128 + ch*2) ^ ((r32&7)<<4)
//   V tile:  [64 ch][32 kv] bf16, byte = (ch*64 + u32*2) ^ ((ch&7)<<3)
__global__ __launch_bounds__(256) void proj_kernel(
    const float* __restrict__ x,
    const float* __restrict__ Wq, const float* __restrict__ bq,
    const float* __restrict__ Wk, const float* __restrict__ bk,
    const float* __restrict__ Wv, const float* __restrict__ bv,
    const float* __restrict__ stats,
    short* __restrict__ qo, char* __restrict__ kws, char* __restrict__ vws) {
    __shared__ char hbuf[64 * 128];  // [64 rows][64 bf16], XOR-swizzled

    int b  = blockIdx.x >> 6;
    int t_ = blockIdx.x & 63;        // 64-row tile index within batch
    int s0 = t_ * 64;
    float mu = stats[b * 2], rs = stats[b * 2 + 1];
    const float* xt = x + ((size_t)b * S_ + s0) * C_;
    int t = threadIdx.x;

#pragma unroll
    for (int i = 0; i < 4; ++i) {
        int fi  = t + 256 * i;       // float4 index within 64x64 tile
        int row = fi >> 4;
        int c4  = fi & 15;
        float4 v = *(const float4*)(xt + row * C_ + c4 * 4);
        unsigned lo = (unsigned)(unsigned short)f2bf((v.x - mu) * rs) |
                      ((unsigned)(unsigned short)f2bf((v.y - mu) * rs) << 16);
        unsigned hi = (unsigned)(unsigned short)f2bf((v.z - mu) * rs) |
                      ((unsigned)(unsigned short)f2bf((v.w - mu) * rs) << 16);
        int off = row * 128 + c4 * 8;
        off ^= (row & 7) << 4;
        *(uint2*)(hbuf + off) = make_uint2(lo, hi);
    }
    __syncthreads();

    int lane = t & 63, w = t >> 6;
    int g = lane >> 4, c = lane & 15;

    auto ld_h = [&](int row, int kcol) -> bf16x8 {
        int off = row * 128 + kcol * 2;
        off ^= (row & 7) << 4;
        return *(const bf16x8*)(hbuf + off);
    };

    // ---- Q and K: D = h @ W^T.  A = h rows 16w..16w+15 ----
    bf16x8 ha[2];
    ha[0] = ld_h(16 * w + c, 8 * g);
    ha[1] = ld_h(16 * w + c, 32 + 8 * g);

    const float QSC = 0.125f * 1.44269504088896340736f;  // C^-0.5 * log2(e)

#pragma unroll
    for (int n = 0; n < 4; ++n) {
        floatx4 aq = {0.f, 0.f, 0.f, 0.f}, ak = {0.f, 0.f, 0.f, 0.f};
#pragma unroll
        for (int kk = 0; kk < 2; ++kk) {
            bf16x8 wq = ld_w_frag(Wq, n, kk, g, c);
            bf16x8 wk = ld_w_frag(Wk, n, kk, g, c);
            aq = __builtin_amdgcn_mfma_f32_16x16x32_bf16(ha[kk], wq, aq, 0, 0, 0);
            ak = __builtin_amdgcn_mfma_f32_16x16x32_bf16(ha[kk], wk, ak, 0, 0, 0);
        }
        float bqv = bq[16 * n + c], bkv = bk[16 * n + c];
#pragma unroll
        for (int r = 0; r < 4; ++r) {
            int rr = 16 * w + 4 * g + r;          // kv row within 64-row tile
            qo[((size_t)b * S_ + s0 + rr) * C_ + 16 * n + c] = f2bf((aq[r] + bqv) * QSC);
            int r32 = rr & 31;
            size_t tb = ((size_t)b * 128 + 2 * t_ + (rr >> 5)) * 4096;
            int koff = (r32 * 128 + (16 * n + c) * 2) ^ ((r32 & 7) << 4);
            *(short*)(kws + tb + koff) = f2bf(ak[r] + bkv);
        }
    }

    // ---- V^T = Wv @ h^T (direct transposed, 32-kv swizzled tile images) ----
    bf16x8 wv[2];
    wv[0] = ld_w_frag(Wv, w, 0, g, c);
    wv[1] = ld_w_frag(Wv, w, 1, g, c);
    float bvr[4];
#pragma unroll
    for (int r = 0; r < 4; ++r) bvr[r] = bv[16 * w + 4 * g + r];

#pragma unroll
    for (int n = 0; n < 4; ++n) {
        floatx4 av = {0.f, 0.f, 0.f, 0.f};
#pragma unroll
        for (int kk = 0; kk < 2; ++kk) {
            bf16x8 hb = ld_h(16 * n + c, 32 * kk + 8 * g);
            av = __builtin_amdgcn_mfma_f32_16x16x32_bf16(wv[kk], hb, av, 0, 0, 0);
        }
        int u   = 16 * n + c;                  // kv col within 64-row tile
        int u32 = u & 31;
        size_t tb = ((size_t)b * 128 + 2 * t_ + (u >> 5)) * 4096;
#pragma unroll
        for (int r = 0; r < 4; ++r) {
            int rr = 16 * w + 4 * g + r;          // channel row
            int voff = (rr * 64 + u32 * 2) ^ ((rr & 7) << 3);
            *(short*)(vws + tb + voff) = f2bf(av[r] + bvr[r]);
        }
    }
}

// ---------------- kernel 3: fold-m flash attention (R15 base) ----------------
// Grid 1024: block = (batch, 128-q-tile, kv-quarter); wave w owns q rows
// q0+32w..+31; K/V read once per wave, reused for both q-subtiles; dbuf.
// NEW: QK accumulator is initialized to -m (register broadcast, same cost as
// zero-init) so MFMA emits S-m directly -> the 16 v_sub per tile before exp2
// are DELETED. Rescale (rare, defer-max) subtracts the delta in-branch.
__global__ __launch_bounds__(256, 4) void flash_kernel(
    const short* __restrict__ qm, const char* __restrict__ kws, const char* __restrict__ vws,
    short* __restrict__ Opart, float2* __restrict__ mlpart) {
    __shared__ char lds[16384];   // [0,8K): K dbuf (2x4KB); [8K,16K): V dbuf

    int bid = blockIdx.x;
    int logical = (bid & 7) * 128 + (bid >> 3);  // XCD swizzle: batch b -> XCD b
    int b = logical >> 7;
    int rest = logical & 127;
    int q0 = (rest >> 2) * 128;
    int quarter = rest & 3;
    int t = threadIdx.x;
    int lane = t & 63, w = t >> 6;
    int g = lane >> 4, c = lane & 15;
    int qw = q0 + 32 * w;

    const char* kbase = kws + (size_t)b * 128 * 4096;
    const char* vbase = vws + (size_t)b * 128 * 4096;
    const short* qp = qm + (size_t)b * S_ * C_;

    // Q^T B-fragments for this wave's two 16-row q-subtiles.
    bf16x8 bqf[2][2];
#pragma unroll
    for (int qi = 0; qi < 2; ++qi) {
        bqf[qi][0] = *(const bf16x8*)(qp + (qw + 16 * qi + c) * C_ + 8 * g);
        bqf[qi][1] = *(const bf16x8*)(qp + (qw + 16 * qi + c) * C_ + 32 + 8 * g);
    }

    floatx4 oacc[2][4];               // [qi][mi]
#pragma unroll
    for (int qi = 0; qi < 2; ++qi)
#pragma unroll
        for (int mi = 0; mi < 4; ++mi) oacc[qi][mi] = (floatx4){0.f, 0.f, 0.f, 0.f};
    // m starts at -64: first tile's need (= relative max) > 8 triggers one
    // rescale that snaps m to the true local max; exp2 stays finite meanwhile.
    float m[2] = {-64.f, -64.f}, nm[2] = {64.f, 64.f}, l[2] = {0.f, 0.f};

    const int xmask  = (c & 7) << 4;   // K row swizzle (16B granule)
    const int vxmask = (c & 7) << 3;   // V row swizzle (8B granule)

    auto STAGE = [&](int bi, int tt) {
        const char* gk = kbase + (size_t)tt * 4096 + t * 16;
        const char* gv = vbase + (size_t)tt * 4096 + t * 16;
        char* lk = lds +        bi * 4096 + t * 16;
        char* lv = lds + 8192 + bi * 4096 + t * 16;
        __builtin_amdgcn_global_load_lds((as1_u32*)gk, (as3_u32*)lk, 16, 0, 0);
        __builtin_amdgcn_global_load_lds((as1_u32*)gv, (as3_u32*)lv, 16, 0, 0);
    };

    // K read: kv row = 16*s + c, col bytes colb (16B granule)
    auto ld_k = [&](const char* buf, int s, int colb) -> bf16x8 {
        return *(const bf16x8*)(buf + s * 2048 + c * 128 + (colb ^ xmask));
    };
    // V read (8B): ch row = 16*mi + c, kv chunk = 16*s + 4*g
    auto ld_v = [&](const char* buf, int mi, int s) -> bf16x4 {
        return *(const bf16x4*)(buf + mi * 1024 + c * 64 + ((32 * s + 8 * g) ^ vxmask));
    };

    auto COMPUTE = [&](int bi) {
        const char* kbuf = lds +        bi * 4096;
        const char* vbuf = lds + 8192 + bi * 4096;
        // K fragments read ONCE, reused for both q-subtiles
        bf16x8 ak[2][2];
#pragma unroll
        for (int s = 0; s < 2; ++s)
#pragma unroll
            for (int kk = 0; kk < 2; ++kk)
                ak[s][kk] = ld_k(kbuf, s, 64 * kk + 16 * g);
        // ---- S^T (32 kv x 32 q), accumulator pre-loaded with -m ----
        floatx4 st[2][2];
        __builtin_amdgcn_s_setprio(1);
#pragma unroll
        for (int qi = 0; qi < 2; ++qi)
#pragma unroll
            for (int s = 0; s < 2; ++s) {
                st[qi][s] = (floatx4){nm[qi], nm[qi], nm[qi], nm[qi]};
                st[qi][s] = __builtin_amdgcn_mfma_f32_16x16x32_bf16(ak[s][0], bqf[qi][0], st[qi][s], 0, 0, 0);
                st[qi][s] = __builtin_amdgcn_mfma_f32_16x16x32_bf16(ak[s][1], bqf[qi][1], st[qi][s], 0, 0, 0);
            }
        __builtin_amdgcn_s_setprio(0);
        // V fragments read ONCE (independent of softmax; issued early)
        bf16x4 av[2][4];
#pragma unroll
        for (int s = 0; s < 2; ++s)
#pragma unroll
            for (int mi = 0; mi < 4; ++mi)
                av[s][mi] = ld_v(vbuf, mi, s);
        // ---- online softmax; st is already (S - m), so mt is RELATIVE ----
        float mt[2], need;
#pragma unroll
        for (int qi = 0; qi < 2; ++qi) {
            float v = fmaxf(fmaxf(st[qi][0][0], st[qi][0][1]), fmaxf(st[qi][0][2], st[qi][0][3]));
            v = fmaxf(v, fmaxf(fmaxf(st[qi][1][0], st[qi][1][1]), fmaxf(st[qi][1][2], st[qi][1][3])));
            v = fmaxf(v, __shfl_xor(v, 16));
            v = fmaxf(v, __shfl_xor(v, 32));
            mt[qi] = v;
        }
        need = fmaxf(mt[0], mt[1]);
        if (!__all(need <= 8.0f)) {
#pragma unroll
            for (int qi = 0; qi < 2; ++qi) {
                float d = fmaxf(mt[qi], 0.f);
                float a = __builtin_amdgcn_exp2f(-d);
                m[qi] += d;
                nm[qi] = -m[qi];
                l[qi] *= a;
#pragma unroll
                for (int mi = 0; mi < 4; ++mi) oacc[qi][mi] *= a;
#pragma unroll
                for (int s = 0; s < 2; ++s)
#pragma unroll
                    for (int r = 0; r < 4; ++r) st[qi][s][r] -= d;
            }
        }
        bf16x4 pb[2][2];
#pragma unroll
        for (int qi = 0; qi < 2; ++qi) {
            float psum = 0.f;
#pragma unroll
            for (int s = 0; s < 2; ++s) {
                float e0 = __builtin_amdgcn_exp2f(st[qi][s][0]);
                float e1 = __builtin_amdgcn_exp2f(st[qi][s][1]);
                float e2 = __builtin_amdgcn_exp2f(st[qi][s][2]);
                float e3 = __builtin_amdgcn_exp2f(st[qi][s][3]);
                psum += (e0 + e1) + (e2 + e3);
                uint2 u = make_uint2(cvt_pk_bf16(e0, e1), cvt_pk_bf16(e2, e3));
                pb[qi][s] = __builtin_bit_cast(bf16x4, u);
            }
            l[qi] += psum;
        }
        // ---- O^T += V^T @ P^T (16 MFMA16; av reused across q-subtiles) ----
        __builtin_amdgcn_s_setprio(1);
#pragma unroll
        for (int qi = 0; qi < 2; ++qi)
#pragma unroll
            for (int s = 0; s < 2; ++s)
#pragma unroll
                for (int mi = 0; mi < 4; ++mi)
                    oacc[qi][mi] = mfma_16x16x16_bf16(av[s][mi], pb[qi][s], oacc[qi][mi]);
        __builtin_amdgcn_s_setprio(0);
    };

    const int base = quarter * 32;
    STAGE(0, base);
    __syncthreads();
    for (int r = 0; r < 32; r += 2) {
        STAGE(1, base + r + 1);
        COMPUTE(0);
        __syncthreads();
        if (r + 2 < 32) STAGE(0, base + r + 2);
        COMPUTE(1);
        __syncthreads();
    }

    // ---- finalize: l reduce across lane groups; write (M,L) + bf16 partial ----
#pragma unroll
    for (int qi = 0; qi < 2; ++qi) {
        l[qi] += __shfl_xor(l[qi], 16);
        l[qi] += __shfl_xor(l[qi], 32);
    }

    size_t prow = (size_t)(quarter * 8 + b) * S_ + q0;
    if (lane < 16) {
#pragma unroll
        for (int qi = 0; qi < 2; ++qi)
            mlpart[prow + 32 * w + 16 * qi + lane] = make_float2(m[qi], l[qi]);
    }

#pragma unroll
    for (int qi = 0; qi < 2; ++qi) {
        short* op = Opart + (prow + 32 * w + 16 * qi + c) * C_;
#pragma unroll
        for (int mi = 0; mi < 4; ++mi) {
            uint2 u = make_uint2(cvt_pk_bf16(oacc[qi][mi][0], oacc[qi][mi][1]),
                                 cvt_pk_bf16(oacc[qi][mi][2], oacc[qi][mi][3]));
            *(uint2*)(op + 16 * mi + 4 * g) = u;
        }
    }
}

// ---------------- kernel 4: 4-way LSE combine + Wo + residual ----------------
__global__ __launch_bounds__(256) void combine_kernel(
    const short* __restrict__ Opart, const float2* __restrict__ mlpart,
    const float* __restrict__ Wo, const float* __restrict__ bo,
    const float* __restrict__ x, float* __restrict__ out) {
    __shared__ char obuf[8192];   // [64 q][64 ch] bf16, XOR-swizzled

    int bid = blockIdx.x;
    int logical = (bid & 7) * 64 + (bid >> 3);  // XCD swizzle: batch b -> XCD b
    int b = logical >> 6;
    int q0 = (logical & 63) * 64;
    int t = threadIdx.x;
    int lane = t & 63, w = t >> 6;
    int g = lane >> 4, c = lane & 15;

    const short*  P[4];
    const float2* ml[4];
#pragma unroll
    for (int h = 0; h < 4; ++h) {
        P[h]  = Opart  + ((size_t)(h * 8 + b) * S_ + q0) * C_;
        ml[h] = mlpart + (size_t)(h * 8 + b) * S_ + q0;
    }

#pragma unroll
    for (int i = 0; i < 16; ++i) {
        int idx = t + 256 * i;
        int q = idx >> 6, ch = idx & 63;
        float2 a0 = ml[0][q], a1 = ml[1][q], a2 = ml[2][q], a3 = ml[3][q];
        float M = fmaxf(fmaxf(a0.x, a1.x), fmaxf(a2.x, a3.x));
        float s0 = __builtin_amdgcn_exp2f(a0.x - M);
        float s1 = __builtin_amdgcn_exp2f(a1.x - M);
        float s2 = __builtin_amdgcn_exp2f(a2.x - M);
        float s3 = __builtin_amdgcn_exp2f(a3.x - M);
        float L  = a0.y * s0 + a1.y * s1 + a2.y * s2 + a3.y * s3;
        float o  = (bf2f(P[0][q * 64 + ch]) * s0 + bf2f(P[1][q * 64 + ch]) * s1 +
                    bf2f(P[2][q * 64 + ch]) * s2 + bf2f(P[3][q * 64 + ch]) * s3) / L;
        int off = (q * 128 + ch * 2) ^ ((q & 7) << 4);
        *(short*)(obuf + off) = f2bf(o);
    }
    __syncthreads();

    // wave w handles q rows q0+16w..+15; out = o @ Wo^T + bo + x
    bf16x8 ao[2];
    {
        int row = 16 * w + c;
        int off0 = (row * 128 + (8 * g) * 2)      ^ ((row & 7) << 4);
        int off1 = (row * 128 + (32 + 8 * g) * 2) ^ ((row & 7) << 4);
        ao[0] = *(const bf16x8*)(obuf + off0);
        ao[1] = *(const bf16x8*)(obuf + off1);
    }
#pragma unroll
    for (int n = 0; n < 4; ++n) {
        floatx4 a = {0.f, 0.f, 0.f, 0.f};
#pragma unroll
        for (int kk = 0; kk < 2; ++kk) {
            bf16x8 bw = ld_w_frag(Wo, n, kk, g, c);
            a = __builtin_amdgcn_mfma_f32_16x16x32_bf16(ao[kk], bw, a, 0, 0, 0);
        }
        float bov = bo[16 * n + c];
#pragma unroll
        for (int r = 0; r < 4; ++r) {
            int srow = q0 + 16 * w + 4 * g + r;
            size_t idx = ((size_t)b * S_ + srow) * C_ + 16 * n + c;
            out[idx] = x[idx] + bov + a[r];
        }
    }
}

extern "C" void kernel_launch(void* const* d_in, const int* in_sizes, int n_in,
                              void* d_out, int out_size, void* d_ws, size_t ws_size,
                              hipStream_t stream) {
    const float* x  = (const float*)d_in[0];
    // d_in[1] = temb (unused by reference)
    const float* Wq = (const float*)d_in[2];
    const float* bq = (const float*)d_in[3];
    const float* Wk = (const float*)d_in[4];
    const float* bk = (const float*)d_in[5];
    const float* Wv = (const float*)d_in[6];
    const float* bv = (const float*)d_in[7];
    const float* Wo = (const float*)d_in[8];
    const float* bo = (const float*)d_in[9];
    float* out = (float*)d_out;

    char* ws = (char*)d_ws;
    float*  partial = (float*)ws;                       // 512 floats
    float*  stats   = (float*)(ws + 2048);              // 16 floats
    short*  q   = (short*)(ws + 4096);                  // [B][S][C] bf16 (4 MB)
    char*   kt  = (char*)(q + (size_t)B_ * S_ * C_);    // [B][128][4096] swizzled K (4 MB)
    char*   vt  = kt + (size_t)B_ * 128 * 4096;         // [B][128][4096] swizzled V^T (4 MB)
    short*  op  = (short*)(vt + (size_t)B_ * 128 * 4096);// [4][B][S][C] bf16 partials (16 MB)
    float2* mlp = (float2*)((char*)op + (size_t)4 * B_ * S_ * C_ * 2); // [4][B][S] (1 MB)

    stats1_kernel<<<256, 256, 0, stream>>>(x, partial);
    stats2_kernel<<<1, 512, 0, stream>>>(partial, stats);
    proj_kernel<<<B_ * (S_ / 64), 256, 0, stream>>>(x, Wq, bq, Wk, bk, Wv, bv, stats, q, kt, vt);
    flash_kernel<<<B_ * (S_ / 128) * 4, 256, 0, stream>>>(q, kt, vt, op, mlp);
    combine_kernel<<<B_ * (S_ / 64), 256, 0, stream>>>(op, mlp, Wo, bo, x, out);
}

// Round 19
// 80.691 us; speedup vs baseline: 1.1367x; 1.0635x over previous
//
#include <hip/hip_runtime.h>
#include <hip/hip_bf16.h>
#include <math.h>

#define B_ 8
#define S_ 4096
#define C_ 64
#define EPSV 1e-5f

using floatx4  = __attribute__((ext_vector_type(4)))  float;
using floatx16 = __attribute__((ext_vector_type(16))) float;
using bf16x8   = __attribute__((ext_vector_type(8)))  short;

typedef __attribute__((address_space(3))) unsigned int       as3_u32;
typedef __attribute__((address_space(1))) const unsigned int as1_u32;

__device__ __forceinline__ short f2bf(float f) {
    unsigned u = __builtin_bit_cast(unsigned, f);
    u = u + 0x7fffu + ((u >> 16) & 1u);   // RNE
    return (short)(u >> 16);
}

__device__ __forceinline__ float bf2f(short s) {
    return __builtin_bit_cast(float, ((unsigned)(unsigned short)s) << 16);
}

__device__ __forceinline__ unsigned cvt_pk_bf16(float lo, float hi) {
    unsigned r;
    asm volatile("v_cvt_pk_bf16_f32 %0, %1, %2" : "=v"(r) : "v"(lo), "v"(hi));
    return r;
}

// swap a's high 32 lanes with b's low 32 lanes (both updated).
__device__ __forceinline__ void perm32swap(unsigned &a, unsigned &b) {
#if __has_builtin(__builtin_amdgcn_permlane32_swap)
    auto r = __builtin_amdgcn_permlane32_swap((int)a, (int)b, false, false);
    a = (unsigned)r[0];
    b = (unsigned)r[1];
#else
    asm volatile("v_permlane32_swap_b32 %0, %1" : "+v"(a), "+v"(b));
#endif
}

// B-fragment from a row-major fp32 64x64 weight matrix.
__device__ __forceinline__ bf16x8 ld_w_frag(const float* __restrict__ W, int n, int kk, int g, int c) {
    const float* p = W + (16 * n + c) * C_ + 32 * kk + 8 * g;
    bf16x8 r;
#pragma unroll
    for (int j = 0; j < 8; ++j) r[j] = f2bf(p[j]);
    return r;
}

// ---------------- kernel 1a: per-chunk partial sums ----------------
__global__ __launch_bounds__(256) void stats1_kernel(const float* __restrict__ x,
                                                     float* __restrict__ partial) {
    int b = blockIdx.x >> 5, chunk = blockIdx.x & 31;
    const float4* xb = (const float4*)x + (size_t)b * 65536 + chunk * 2048;
    float s = 0.f, ss = 0.f;
#pragma unroll
    for (int i = 0; i < 8; ++i) {
        float4 v = xb[threadIdx.x + i * 256];
        s  += v.x + v.y + v.z + v.w;
        ss += v.x * v.x + v.y * v.y + v.z * v.z + v.w * v.w;
    }
    for (int off = 32; off > 0; off >>= 1) {
        s  += __shfl_down(s, off);
        ss += __shfl_down(ss, off);
    }
    __shared__ float sm[4], ssm[4];
    int wid = threadIdx.x >> 6, lane = threadIdx.x & 63;
    if (lane == 0) { sm[wid] = s; ssm[wid] = ss; }
    __syncthreads();
    if (threadIdx.x == 0) {
        partial[blockIdx.x * 2]     = sm[0] + sm[1] + sm[2] + sm[3];
        partial[blockIdx.x * 2 + 1] = ssm[0] + ssm[1] + ssm[2] + ssm[3];
    }
}

// ---------------- kernel 1b: finalize mean / rsqrt(var) ----------------
__global__ __launch_bounds__(512) void stats2_kernel(const float* __restrict__ partial,
                                                     float* __restrict__ stats) {
    int w = threadIdx.x >> 6, lane = threadIdx.x & 63;  // wave w = batch w
    float s = 0.f, ss = 0.f;
    if (lane < 32) {
        s  = partial[(w * 32 + lane) * 2];
        ss = partial[(w * 32 + lane) * 2 + 1];
    }
    for (int off = 16; off > 0; off >>= 1) {
        s  += __shfl_down(s, off);
        ss += __shfl_down(ss, off);
    }
    if (lane == 0) {
        const float invN = 1.0f / (float)(S_ * C_);
        float mu  = s * invN;
        float var = ss * invN - mu * mu;
        stats[w * 2]     = mu;
        stats[w * 2 + 1] = rsqrtf(var + EPSV);
    }
}

// ---------------- kernel 2: normalize + Q/K/V^T projections ----------------
// K and V^T are written as per-32-kv TILE IMAGES (4096 B each), XOR-swizzled
// exactly as the flash kernel's LDS wants them (both-sides rule).
//   K tile:  [32 kv][64 ch] bf16, byte = (r32*128 + ch*2) ^ ((r32&7)<<4)
//   V tile:  [64 ch][32 kv] bf16, byte = (ch*64 + u32*2) ^ (((ch>>1)&3)<<4)
// (V swizzle at 16B granule so flash's b128 V reads stay contiguous.)
__global__ __launch_bounds__(256) void proj_kernel(
    const float* __restrict__ x,
    const float* __restrict__ Wq, const float* __restrict__ bq,
    const float* __restrict__ Wk, const float* __restrict__ bk,
    const float* __restrict__ Wv, const float* __restrict__ bv,
    const float* __restrict__ stats,
    short* __restrict__ qo, char* __restrict__ kws, char* __restrict__ vws) {
    __shared__ char hbuf[64 * 128];  // [64 rows][64 bf16], XOR-swizzled

    int b  = blockIdx.x >> 6;
    int t_ = blockIdx.x & 63;        // 64-row tile index within batch
    int s0 = t_ * 64;
    float mu = stats[b * 2], rs = stats[b * 2 + 1];
    const float* xt = x + ((size_t)b * S_ + s0) * C_;
    int t = threadIdx.x;

#pragma unroll
    for (int i = 0; i < 4; ++i) {
        int fi  = t + 256 * i;       // float4 index within 64x64 tile
        int row = fi >> 4;
        int c4  = fi & 15;
        float4 v = *(const float4*)(xt + row * C_ + c4 * 4);
        unsigned lo = (unsigned)(unsigned short)f2bf((v.x - mu) * rs) |
                      ((unsigned)(unsigned short)f2bf((v.y - mu) * rs) << 16);
        unsigned hi = (unsigned)(unsigned short)f2bf((v.z - mu) * rs) |
                      ((unsigned)(unsigned short)f2bf((v.w - mu) * rs) << 16);
        int off = row * 128 + c4 * 8;
        off ^= (row & 7) << 4;
        *(uint2*)(hbuf + off) = make_uint2(lo, hi);
    }
    __syncthreads();

    int lane = t & 63, w = t >> 6;
    int g = lane >> 4, c = lane & 15;

    auto ld_h = [&](int row, int kcol) -> bf16x8 {
        int off = row * 128 + kcol * 2;
        off ^= (row & 7) << 4;
        return *(const bf16x8*)(hbuf + off);
    };

    // ---- Q and K: D = h @ W^T.  A = h rows 16w..16w+15 ----
    bf16x8 ha[2];
    ha[0] = ld_h(16 * w + c, 8 * g);
    ha[1] = ld_h(16 * w + c, 32 + 8 * g);

    const float QSC = 0.125f * 1.44269504088896340736f;  // C^-0.5 * log2(e)

#pragma unroll
    for (int n = 0; n < 4; ++n) {
        floatx4 aq = {0.f, 0.f, 0.f, 0.f}, ak = {0.f, 0.f, 0.f, 0.f};
#pragma unroll
        for (int kk = 0; kk < 2; ++kk) {
            bf16x8 wq = ld_w_frag(Wq, n, kk, g, c);
            bf16x8 wk = ld_w_frag(Wk, n, kk, g, c);
            aq = __builtin_amdgcn_mfma_f32_16x16x32_bf16(ha[kk], wq, aq, 0, 0, 0);
            ak = __builtin_amdgcn_mfma_f32_16x16x32_bf16(ha[kk], wk, ak, 0, 0, 0);
        }
        float bqv = bq[16 * n + c], bkv = bk[16 * n + c];
#pragma unroll
        for (int r = 0; r < 4; ++r) {
            int rr = 16 * w + 4 * g + r;          // kv row within 64-row tile
            qo[((size_t)b * S_ + s0 + rr) * C_ + 16 * n + c] = f2bf((aq[r] + bqv) * QSC);
            int r32 = rr & 31;
            size_t tb = ((size_t)b * 128 + 2 * t_ + (rr >> 5)) * 4096;
            int koff = (r32 * 128 + (16 * n + c) * 2) ^ ((r32 & 7) << 4);
            *(short*)(kws + tb + koff) = f2bf(ak[r] + bkv);
        }
    }

    // ---- V^T = Wv @ h^T (direct transposed, 32-kv swizzled tile images) ----
    bf16x8 wv[2];
    wv[0] = ld_w_frag(Wv, w, 0, g, c);
    wv[1] = ld_w_frag(Wv, w, 1, g, c);
    float bvr[4];
#pragma unroll
    for (int r = 0; r < 4; ++r) bvr[r] = bv[16 * w + 4 * g + r];

#pragma unroll
    for (int n = 0; n < 4; ++n) {
        floatx4 av = {0.f, 0.f, 0.f, 0.f};
#pragma unroll
        for (int kk = 0; kk < 2; ++kk) {
            bf16x8 hb = ld_h(16 * n + c, 32 * kk + 8 * g);
            av = __builtin_amdgcn_mfma_f32_16x16x32_bf16(wv[kk], hb, av, 0, 0, 0);
        }
        int u   = 16 * n + c;                  // kv col within 64-row tile
        int u32 = u & 31;
        size_t tb = ((size_t)b * 128 + 2 * t_ + (u >> 5)) * 4096;
#pragma unroll
        for (int r = 0; r < 4; ++r) {
            int rr = 16 * w + 4 * g + r;          // channel row
            int voff = (rr * 64 + u32 * 2) ^ (((rr >> 1) & 3) << 4);
            *(short*)(vws + tb + voff) = f2bf(av[r] + bvr[r]);
        }
    }
}

// ---------------- kernel 3: 32x32-MFMA flash attention ----------------
// Grid 1024: block = (batch, 128-q-tile, kv-quarter); wave w owns q rows
// q0+32w..+31; lane holds ONE q column (q5=lane&31). QK and PV both use the
// full-rate 32x32x16 bf16 MFMA (R17 established the legacy 16x16x16 is
// quarter-rate ~20cyc: PV was 320cyc/tile of matrix pipe; now 32cyc).
// PV B-fragment built from QK accumulator via 8 cvt_pk + 4 permlane32_swap.
// fold-m (R18): QK C-init = -m so MFMA emits S-m directly.
__global__ __launch_bounds__(256, 4) void flash_kernel(
    const short* __restrict__ qm, const char* __restrict__ kws, const char* __restrict__ vws,
    short* __restrict__ Opart, float2* __restrict__ mlpart) {
    __shared__ char lds[16384];   // [0,8K): K dbuf (2x4KB); [8K,16K): V dbuf

    int bid = blockIdx.x;
    int logical = (bid & 7) * 128 + (bid >> 3);  // XCD swizzle: batch b -> XCD b
    int b = logical >> 7;
    int rest = logical & 127;
    int q0 = (rest >> 2) * 128;
    int quarter = rest & 3;
    int t = threadIdx.x;
    int lane = t & 63, w = t >> 6;
    int r5 = lane & 31, hi = lane >> 5;
    int qw = q0 + 32 * w;

    const char* kbase = kws + (size_t)b * 128 * 4096;
    const char* vbase = vws + (size_t)b * 128 * 4096;
    const short* qp = qm + (size_t)b * S_ * C_;

    // Q^T B-fragments: lane (q5=r5, hi) holds Q[qw+q5][16kk+8hi .. +8]
    bf16x8 bq[4];
#pragma unroll
    for (int kk = 0; kk < 4; ++kk)
        bq[kk] = *(const bf16x8*)(qp + (qw + r5) * C_ + 16 * kk + 8 * hi);

    floatx16 oacc[2];   // O^T[ch-half m][16 ch' rows], col q5
#pragma unroll
    for (int mm = 0; mm < 2; ++mm)
#pragma unroll
        for (int i = 0; i < 16; ++i) oacc[mm][i] = 0.f;
    // fold-m: m starts at -64; first tile's relative max > 8 snaps it.
    float m = -64.f, nm = 64.f, l = 0.f;

    const int kxm = (r5 & 7) << 4;          // K row swizzle (16B granule)
    const int vxm = ((r5 >> 1) & 3) << 4;   // V row swizzle (16B granule)

    auto STAGE = [&](int bi, int tt) {
        const char* gk = kbase + (size_t)tt * 4096 + t * 16;
        const char* gv = vbase + (size_t)tt * 4096 + t * 16;
        char* lk = lds +        bi * 4096 + t * 16;
        char* lv = lds + 8192 + bi * 4096 + t * 16;
        __builtin_amdgcn_global_load_lds((as1_u32*)gk, (as3_u32*)lk, 16, 0, 0);
        __builtin_amdgcn_global_load_lds((as1_u32*)gv, (as3_u32*)lv, 16, 0, 0);
    };

    // K A-frag: row r5, ch = 16kk+8hi..+8
    auto ld_k = [&](const char* buf, int kk) -> bf16x8 {
        return *(const bf16x8*)(buf + r5 * 128 + ((32 * kk + 16 * hi) ^ kxm));
    };
    // V A-frag: row 32mm+r5 (ch), kv = 16s+8hi..+8
    auto ld_v = [&](const char* buf, int mm, int s) -> bf16x8 {
        return *(const bf16x8*)(buf + (32 * mm + r5) * 64 + ((32 * s + 16 * hi) ^ vxm));
    };

    auto COMPUTE = [&](int bi) {
        const char* kbuf = lds +        bi * 4096;
        const char* vbuf = lds + 8192 + bi * 4096;
        // ---- S^T[32kv][32q] = K @ Q^T, C pre-loaded with -m ----
        floatx16 st;
#pragma unroll
        for (int i = 0; i < 16; ++i) st[i] = nm;
        __builtin_amdgcn_s_setprio(1);
#pragma unroll
        for (int kk = 0; kk < 4; ++kk) {
            bf16x8 ak = ld_k(kbuf, kk);
            st = __builtin_amdgcn_mfma_f32_32x32x16_bf16(ak, bq[kk], st, 0, 0, 0);
        }
        __builtin_amdgcn_s_setprio(0);
        // V fragments (independent of softmax; issued early)
        bf16x8 av[2][2];
#pragma unroll
        for (int mm = 0; mm < 2; ++mm)
#pragma unroll
            for (int s = 0; s < 2; ++s)
                av[mm][s] = ld_v(vbuf, mm, s);
        // ---- online softmax: lane owns q=qw+q5; st already (S - m) ----
        float mt = st[0];
#pragma unroll
        for (int i = 1; i < 16; ++i) mt = fmaxf(mt, st[i]);
        mt = fmaxf(mt, __shfl_xor(mt, 32));
        if (!__all(mt <= 8.0f)) {   // defer-max (T13)
            float d = fmaxf(mt, 0.f);
            float a = __builtin_amdgcn_exp2f(-d);
            m += d;
            nm = -m;
            l *= a;
#pragma unroll
            for (int mm = 0; mm < 2; ++mm) oacc[mm] *= a;
#pragma unroll
            for (int i = 0; i < 16; ++i) st[i] -= d;
        }
        float e[16], psum = 0.f;
#pragma unroll
        for (int i = 0; i < 16; ++i) e[i] = __builtin_amdgcn_exp2f(st[i]);
#pragma unroll
        for (int i = 0; i < 16; ++i) psum += e[i];
        l += psum;
        // ---- pack P + permlane32_swap -> PV B-fragments ----
        unsigned wd[8];
#pragma unroll
        for (int j = 0; j < 8; ++j) wd[j] = cvt_pk_bf16(e[2 * j], e[2 * j + 1]);
        perm32swap(wd[0], wd[2]);
        perm32swap(wd[1], wd[3]);
        perm32swap(wd[4], wd[6]);
        perm32swap(wd[5], wd[7]);
        uint4 u0 = make_uint4(wd[0], wd[1], wd[2], wd[3]);
        uint4 u1 = make_uint4(wd[4], wd[5], wd[6], wd[7]);
        bf16x8 bp0 = __builtin_bit_cast(bf16x8, u0);
        bf16x8 bp1 = __builtin_bit_cast(bf16x8, u1);
        // ---- O^T += V^T @ P^T (4x full-rate 32x32x16) ----
        __builtin_amdgcn_s_setprio(1);
#pragma unroll
        for (int mm = 0; mm < 2; ++mm) {
            oacc[mm] = __builtin_amdgcn_mfma_f32_32x32x16_bf16(av[mm][0], bp0, oacc[mm], 0, 0, 0);
            oacc[mm] = __builtin_amdgcn_mfma_f32_32x32x16_bf16(av[mm][1], bp1, oacc[mm], 0, 0, 0);
        }
        __builtin_amdgcn_s_setprio(0);
    };

    const int base = quarter * 32;
    STAGE(0, base);
    __syncthreads();
    for (int r = 0; r < 32; r += 2) {
        STAGE(1, base + r + 1);
        COMPUTE(0);
        __syncthreads();
        if (r + 2 < 32) STAGE(0, base + r + 2);
        COMPUTE(1);
        __syncthreads();
    }

    // ---- finalize: merge half-wave l; write (M,L) + bf16 partial ----
    l += __shfl_xor(l, 32);

    size_t prow = (size_t)(quarter * 8 + b) * S_ + q0;
    if (lane < 32)
        mlpart[prow + 32 * w + r5] = make_float2(m, l);

    short* op = Opart + (prow + 32 * w + r5) * C_;
#pragma unroll
    for (int mm = 0; mm < 2; ++mm) {
#pragma unroll
        for (int j = 0; j < 4; ++j) {
            int ch = 32 * mm + 8 * j + 4 * hi;
            uint2 u = make_uint2(cvt_pk_bf16(oacc[mm][4 * j],     oacc[mm][4 * j + 1]),
                                 cvt_pk_bf16(oacc[mm][4 * j + 2], oacc[mm][4 * j + 3]));
            *(uint2*)(op + ch) = u;
        }
    }
}

// ---------------- kernel 4: 4-way LSE combine + Wo + residual ----------------
__global__ __launch_bounds__(256) void combine_kernel(
    const short* __restrict__ Opart, const float2* __restrict__ mlpart,
    const float* __restrict__ Wo, const float* __restrict__ bo,
    const float* __restrict__ x, float* __restrict__ out) {
    __shared__ char obuf[8192];   // [64 q][64 ch] bf16, XOR-swizzled

    int bid = blockIdx.x;
    int logical = (bid & 7) * 64 + (bid >> 3);  // XCD swizzle: batch b -> XCD b
    int b = logical >> 6;
    int q0 = (logical & 63) * 64;
    int t = threadIdx.x;
    int lane = t & 63, w = t >> 6;
    int g = lane >> 4, c = lane & 15;

    const short*  P[4];
    const float2* ml[4];
#pragma unroll
    for (int h = 0; h < 4; ++h) {
        P[h]  = Opart  + ((size_t)(h * 8 + b) * S_ + q0) * C_;
        ml[h] = mlpart + (size_t)(h * 8 + b) * S_ + q0;
    }

#pragma unroll
    for (int i = 0; i < 16; ++i) {
        int idx = t + 256 * i;
        int q = idx >> 6, ch = idx & 63;
        float2 a0 = ml[0][q], a1 = ml[1][q], a2 = ml[2][q], a3 = ml[3][q];
        float M = fmaxf(fmaxf(a0.x, a1.x), fmaxf(a2.x, a3.x));
        float s0 = __builtin_amdgcn_exp2f(a0.x - M);
        float s1 = __builtin_amdgcn_exp2f(a1.x - M);
        float s2 = __builtin_amdgcn_exp2f(a2.x - M);
        float s3 = __builtin_amdgcn_exp2f(a3.x - M);
        float L  = a0.y * s0 + a1.y * s1 + a2.y * s2 + a3.y * s3;
        float o  = (bf2f(P[0][q * 64 + ch]) * s0 + bf2f(P[1][q * 64 + ch]) * s1 +
                    bf2f(P[2][q * 64 + ch]) * s2 + bf2f(P[3][q * 64 + ch]) * s3) / L;
        int off = (q * 128 + ch * 2) ^ ((q & 7) << 4);
        *(short*)(obuf + off) = f2bf(o);
    }
    __syncthreads();

    // wave w handles q rows q0+16w..+15; out = o @ Wo^T + bo + x
    bf16x8 ao[2];
    {
        int row = 16 * w + c;
        int off0 = (row * 128 + (8 * g) * 2)      ^ ((row & 7) << 4);
        int off1 = (row * 128 + (32 + 8 * g) * 2) ^ ((row & 7) << 4);
        ao[0] = *(const bf16x8*)(obuf + off0);
        ao[1] = *(const bf16x8*)(obuf + off1);
    }
#pragma unroll
    for (int n = 0; n < 4; ++n) {
        floatx4 a = {0.f, 0.f, 0.f, 0.f};
#pragma unroll
        for (int kk = 0; kk < 2; ++kk) {
            bf16x8 bw = ld_w_frag(Wo, n, kk, g, c);
            a = __builtin_amdgcn_mfma_f32_16x16x32_bf16(ao[kk], bw, a, 0, 0, 0);
        }
        float bov = bo[16 * n + c];
#pragma unroll
        for (int r = 0; r < 4; ++r) {
            int srow = q0 + 16 * w + 4 * g + r;
            size_t idx = ((size_t)b * S_ + srow) * C_ + 16 * n + c;
            out[idx] = x[idx] + bov + a[r];
        }
    }
}

extern "C" void kernel_launch(void* const* d_in, const int* in_sizes, int n_in,
                              void* d_out, int out_size, void* d_ws, size_t ws_size,
                              hipStream_t stream) {
    const float* x  = (const float*)d_in[0];
    // d_in[1] = temb (unused by reference)
    const float* Wq = (const float*)d_in[2];
    const float* bq = (const float*)d_in[3];
    const float* Wk = (const float*)d_in[4];
    const float* bk = (const float*)d_in[5];
    const float* Wv = (const float*)d_in[6];
    const float* bv = (const float*)d_in[7];
    const float* Wo = (const float*)d_in[8];
    const float* bo = (const float*)d_in[9];
    float* out = (float*)d_out;

    char* ws = (char*)d_ws;
    float*  partial = (float*)ws;                       // 512 floats
    float*  stats   = (float*)(ws + 2048);              // 16 floats
    short*  q   = (short*)(ws + 4096);                  // [B][S][C] bf16 (4 MB)
    char*   kt  = (char*)(q + (size_t)B_ * S_ * C_);    // [B][128][4096] swizzled K (4 MB)
    char*   vt  = kt + (size_t)B_ * 128 * 4096;         // [B][128][4096] swizzled V^T (4 MB)
    short*  op  = (short*)(vt + (size_t)B_ * 128 * 4096);// [4][B][S][C] bf16 partials (16 MB)
    float2* mlp = (float2*)((char*)op + (size_t)4 * B_ * S_ * C_ * 2); // [4][B][S] (1 MB)

    stats1_kernel<<<256, 256, 0, stream>>>(x, partial);
    stats2_kernel<<<1, 512, 0, stream>>>(partial, stats);
    proj_kernel<<<B_ * (S_ / 64), 256, 0, stream>>>(x, Wq, bq, Wk, bk, Wv, bv, stats, q, kt, vt);
    flash_kernel<<<B_ * (S_ / 128) * 4, 256, 0, stream>>>(q, kt, vt, op, mlp);
    combine_kernel<<<B_ * (S_ / 64), 256, 0, stream>>>(op, mlp, Wo, bo, x, out);
}